// Round 1
// baseline (87.298 us; speedup 1.0000x reference)
//
#include <hip/hip_runtime.h>

#define BB 8
#define CC 19
#define HH 256
#define WW 256
#define HWW 65536   // H*W
#define IT 8        // rows per k_edt block
#define BIGF 3.0e12f

// ws layout:
// [0, 2MB)     : g2     [B,H,W] float  (squared row distance)
// [2MB, 4MB)   : ce     [B,H,W] float  (unweighted cross-entropy)
// [4MB, +2KB)  : rowany int[512]       (per 4-row-block boundary flag)

// 512 threads = 8 waves/block, 2 blocks/CU -> 4 waves/SIMD (2x the old 4px/float4
// version). Each thread owns 2 pixels (float2). All 19 class loads are issued
// into registers BEFORE the first barrier so the full x-stream is in flight
// when the barrier's vmcnt(0) drain hits; post-barrier compute is wait-free.
__global__ __launch_bounds__(512, 4) void k_bnd_ce(
    const float* __restrict__ x, const int* __restrict__ tgt,
    float* __restrict__ g2, float* __restrict__ ce,
    int* __restrict__ rowany, float* __restrict__ out)
{
    const int blk = blockIdx.x;
    const int b   = blk >> 6;            // image
    const int i0  = (blk & 63) << 2;     // first of 4 rows
    const int j   = threadIdx.x;

    __shared__ int trow[6][WW];          // rows i0-1 .. i0+4 (clamped)
    __shared__ int bflag[4][WW];
    __shared__ int s_any;

    if (blk == 0 && j == 0) out[0] = 0.0f;   // zero accumulator for k_edt_red
    if (j == 0) s_any = 0;

    const int r  = j >> 7;               // row within block (0..3)
    const int c0 = (j & 127) << 1;       // first of 2 columns (even)
    const int h  = i0 + r;

    // --- issue the 6 tgt rows first (oldest in vmcnt queue -> their wait
    //     doesn't drain the x-stream), 3 coalesced entries/thread ---
    const int* tbase = tgt + b * HWW;
    int tv[3];
#pragma unroll
    for (int k = 0; k < 3; ++k) {
        int idx = j + (k << 9);          // 0..1535 over 6x256
        int rr = idx >> 8, cc = idx & 255;
        int hh = min(max(i0 - 1 + rr, 0), HH - 1);
        tv[k] = tbase[hh * WW + cc];     // coalesced
    }

    // --- issue ALL 19 class loads (float2/thread, 8B coalesced) up front ---
    const float* px = x + ((size_t)(b * CC) * HH + h) * WW + c0;
    float2 v[CC];
#pragma unroll
    for (int c = 0; c < CC; ++c)
        v[c] = *(const float2*)(px + (size_t)c * HWW);

#pragma unroll
    for (int k = 0; k < 3; ++k) {
        int idx = j + (k << 9);
        trow[idx >> 8][idx & 255] = tv[k];
    }
    __syncthreads();

    // --- 3x3 morphological gradient (edge padding) for 2 pixels ---
    int anyb = 0;
#pragma unroll
    for (int t = 0; t < 2; ++t) {
        int c = c0 + t;
        int cm = max(c - 1, 0), cp = min(c + 1, WW - 1);
        int mx = trow[r][cm], mn = mx;
#pragma unroll
        for (int rr = 0; rr < 3; ++rr) {
            int a0 = trow[r + rr][cm], a1 = trow[r + rr][c], a2 = trow[r + rr][cp];
            mx = max(mx, max(a0, max(a1, a2)));
            mn = min(mn, min(a0, min(a1, a2)));
        }
        int bnd = (mx != mn) ? 1 : 0;
        bflag[r][c] = bnd;
        anyb |= bnd;
    }
    unsigned long long msk = __ballot(anyb);
    if ((j & 63) == 0 && msk) s_any = 1;      // idempotent LDS store
    __syncthreads();                          // bflag complete; s_any final
    if (j == 0) rowany[blk] = s_any;

    // --- per-row 1D distance (expanding search; dense boundaries -> ~1 iter) ---
    float gv[2];
#pragma unroll
    for (int t = 0; t < 2; ++t) {
        int c = c0 + t;
        float mind = 1e6f;                    // INF; INF^2 = 1e12 matches reference
        for (int d = 0; d < WW; ++d) {
            int lo = c - d, hi = c + d;
            if ((lo >= 0 && bflag[r][lo]) || (hi < WW && bflag[r][hi])) {
                mind = (float)d; break;
            }
        }
        gv[t] = mind * mind;
    }
    *(float2*)(g2 + (size_t)(b * HH + h) * WW + c0) = make_float2(gv[0], gv[1]);

    // --- unweighted CE from the staged registers ---
    // max-subtraction dropped: inputs ~N(0,1), exp() well-conditioned
    // target logit selected in-register (compile-time indices -> no scratch)
    const int t0 = trow[r + 1][c0], t1 = trow[r + 1][c0 + 1];
    float sx = 0.0f, sy = 0.0f, xv0 = 0.0f, xv1 = 0.0f;
#pragma unroll
    for (int c = 0; c < CC; ++c) {
        sx += expf(v[c].x); sy += expf(v[c].y);
        xv0 = (c == t0) ? v[c].x : xv0;
        xv1 = (c == t1) ? v[c].y : xv1;
    }
    *(float2*)(ce + (size_t)(b * HH + h) * WW + c0) =
        make_float2(logf(sx) - xv0, logf(sy) - xv1);
}

__global__ __launch_bounds__(256) void k_edt_red(
    const float* __restrict__ g2, const float* __restrict__ ce,
    const int* __restrict__ rowany, float* __restrict__ out)
{
    const int b  = blockIdx.x >> 5;           // 32 blocks per image
    const int i0 = (blockIdx.x & 31) * IT;
    const int j  = threadIdx.x;               // column

    __shared__ int s_has;
    __shared__ float wsum[4];
    if (j == 0) s_has = 0;
    int ra = (j < 64) ? rowany[b * 64 + j] : 0;
    unsigned long long mk = __ballot(ra != 0);
    __syncthreads();
    if ((j & 63) == 0 && mk) s_has = 1;
    __syncthreads();
    const int has = s_has;

    // --- column EDT with exact early-exit outward scan ---
    float md[IT];
#pragma unroll
    for (int r = 0; r < IT; ++r) md[r] = BIGF;
    const float* gcol = g2 + (size_t)b * HWW + j;
    const int c0 = i0 + 4;                    // |i - c0| <= 4 for i in [i0, i0+7]
    for (int d0 = 0; d0 < HH; d0 += 4) {
        float gl[4], gr[4];
        int   kl[4], kr[4];
#pragma unroll
        for (int t = 0; t < 4; ++t) {
            int d = d0 + t;
            kl[t] = c0 - d; kr[t] = c0 + d;
            gl[t] = (kl[t] >= 0 && kl[t] < HH) ? gcol[(size_t)kl[t] * WW] : BIGF;
            gr[t] = (kr[t] >= 0 && kr[t] < HH) ? gcol[(size_t)kr[t] * WW] : BIGF;
        }
#pragma unroll
        for (int t = 0; t < 4; ++t) {
#pragma unroll
            for (int r = 0; r < IT; ++r) {
                float dl = (float)(i0 + r - kl[t]);   // exact in fp32 (<=255^2)
                float dr = (float)(i0 + r - kr[t]);
                md[r] = fminf(md[r], fmaf(dl, dl, gl[t]));
                md[r] = fminf(md[r], fmaf(dr, dr, gr[t]));
            }
        }
        float bm = md[0];
#pragma unroll
        for (int r = 1; r < IT; ++r) bm = fmaxf(bm, md[r]);
        // remaining d >= d0+4  =>  |i-k| >= d-4 >= d0  =>  value >= d0^2; exact pruning
        float fut = (float)(d0 * d0);
        if (fut > bm) break;
    }

    float acc = 0.0f;
#pragma unroll
    for (int r = 0; r < IT; ++r) {
        float dist = sqrtf(md[r]);
        float w = has ? expf(-dist / 5.0f) : 1.0f;
        acc += ce[((size_t)b * HH + i0 + r) * WW + j] * w;   // coalesced
    }

    // wave64 shuffle reduce -> block -> one atomic
    for (int off = 32; off > 0; off >>= 1)
        acc += __shfl_down(acc, off, 64);
    const int lane = j & 63, wid = j >> 6;
    if (lane == 0) wsum[wid] = acc;
    __syncthreads();
    if (j == 0) {
        float tot = wsum[0] + wsum[1] + wsum[2] + wsum[3];
        atomicAdd(out, tot * (1.0f / (float)(BB * HWW)));
    }
}

extern "C" void kernel_launch(void* const* d_in, const int* in_sizes, int n_in,
                              void* d_out, int out_size, void* d_ws, size_t ws_size,
                              hipStream_t stream) {
    const float* x   = (const float*)d_in[0];
    const int*   tgt = (const int*)d_in[1];
    float*       out = (float*)d_out;

    char* ws = (char*)d_ws;
    float* g2     = (float*)ws;
    float* ce     = (float*)(ws + (size_t)BB * HWW * sizeof(float));
    int*   rowany = (int*)  (ws + (size_t)2 * BB * HWW * sizeof(float));

    k_bnd_ce <<<BB * (HH / 4), 512, 0, stream>>>(x, tgt, g2, ce, rowany, out);
    k_edt_red<<<BB * (HH / IT), 256, 0, stream>>>(g2, ce, rowany, out);
}